// Round 3
// baseline (262.105 us; speedup 1.0000x reference)
//
#include <hip/hip_runtime.h>

// AdultConnectomeNetwork: 3 layers of xt = A_sp @ (W_sp @ xt) + bias.
// Round 18: back to 16-lane fp16x2 layout (r15, 3125 blocks = max waves) with
// a TRUE depth-2 gather pipeline. r15/r17 only pipelined the kv stream; the
// random gathers were issued and consumed in the same iteration, so each
// iteration serialized on ~300cy of L2 gather latency (r17's halved wave
// count made it worse: 259us). Now kv is held two iterations ahead, so
// gathers for iter it+1 are issued from ARRIVED kv while iter it computes.
//  - uint4 kv loads (2/iter), __launch_bounds__(256,8) for 8 waves/SIMD.
//  - fp32 accumulation, identical edge order => numerics identical to r15.
//  - Rows padded to multiple-of-8 edges (zero kv = exact no-op).
//  - Scaled fp16 state: state_l = xt_l*256^-l, exact pow2 rescale in
//    epilogues, x2^24 at the end (round 13; overflow-proof).
//  - Sort: two-pass LDS-staged counting sort (rounds 9-13), unchanged.
// Hardening: computed indices clamped (logic error -> absmax fail, not fault).

#define NN 50000
#define NNZ_E 1600000
#define NB (NN * 32)
#define CHUNK 6144
#define NBLK1 ((NNZ_E + CHUNK - 1) / CHUNK)      // 261
#define NBIN ((NN + 127) / 128)                  // 391 bins of 128 rows
#define NH (NBIN * NBLK1)                        // 102051
#define CAP2 5120                                // bin window cap (mean 4092, +16 sigma)
#define BCAP 6144                                // padded per-bin capacity
#define LENP (NBIN * BCAP)                       // 2402304 padded slots
#define SCAN_NBLK ((NH + 255) / 256)             // 399

__device__ __forceinline__ int clampi(int v, int hi) {  // [0, hi]
    v = v < 0 ? 0 : v;
    return v > hi ? hi : v;
}

__device__ __forceinline__ unsigned short f2h(float v) {
    union { _Float16 h; unsigned short u; } cv;
    cv.h = (_Float16)v;
    return cv.u;
}

__device__ __forceinline__ float kv_val(unsigned kv) {
    union { unsigned short u; _Float16 h; } cv;
    cv.u = (unsigned short)(kv >> 16);
    return (float)cv.h;
}

__device__ __forceinline__ unsigned u4_at(const uint4& v, int j) {
    switch (j & 3) {
        case 0: return v.x;
        case 1: return v.y;
        case 2: return v.z;
        default: return v.w;
    }
}

// Per-(chunk,bin) histogram matrix, bin-major. LDS only, no global atomics.
__global__ __launch_bounds__(256) void hist_kernel(const int* __restrict__ row,
                                                   int* __restrict__ hist1) {
    __shared__ int h[NBIN];
    int blk = blockIdx.x, tid = threadIdx.x;
    for (int j = tid; j < NBIN; j += 256) h[j] = 0;
    __syncthreads();
    int base = blk * CHUNK;
    int n = NNZ_E - base; if (n > CHUNK) n = CHUNK;
    for (int i = tid; i < n; i += 256)
        atomicAdd(&h[clampi(row[base + i], NN - 1) >> 7], 1);
    __syncthreads();
    for (int j = tid; j < NBIN; j += 256) hist1[j * NBLK1 + blk] = h[j];
}

// Exclusive scan within 256-blocks; bsum[blk] = block total.
__global__ void scan_local_kernel(int* __restrict__ data, int n, int* __restrict__ bsum) {
    __shared__ int s[256];
    int i = blockIdx.x * 256 + threadIdx.x;
    int v = (i < n) ? data[i] : 0;
    s[threadIdx.x] = v;
    __syncthreads();
    for (int off = 1; off < 256; off <<= 1) {
        int t = (threadIdx.x >= off) ? s[threadIdx.x - off] : 0;
        __syncthreads();
        s[threadIdx.x] += t;
        __syncthreads();
    }
    if (i < n) data[i] = s[threadIdx.x] - v;     // exclusive within block
    if (threadIdx.x == 255) bsum[blockIdx.x] = s[threadIdx.x];
}

// One block, 512 threads: exclusive scan of bsum[m], m <= 512 (m = 399).
__global__ void scan_tops_kernel(int* __restrict__ bsum, int m) {
    __shared__ int s[512];
    int t = threadIdx.x;
    int v = (t < m) ? bsum[t] : 0;
    s[t] = v;
    __syncthreads();
    for (int off = 1; off < 512; off <<= 1) {
        int u = (t >= off) ? s[t - off] : 0;
        __syncthreads();
        s[t] += u;
        __syncthreads();
    }
    if (t < m) bsum[t] = s[t] - v;               // exclusive
}

__global__ void fin_add_kernel(int* __restrict__ data, int n, const int* __restrict__ bsum) {
    int i = blockIdx.x * blockDim.x + threadIdx.x;
    if (i < n) data[i] += bsum[i >> 8];
}

// binstart[j] = scanned hist1[j*NBLK1].
__global__ void binstart_kernel(const int* __restrict__ hist1, int* __restrict__ binstart) {
    int j = blockIdx.x * blockDim.x + threadIdx.x;
    if (j < NBIN) binstart[j] = hist1[j * NBLK1];
    if (j == 0) binstart[NBIN] = NNZ_E;
}

// Pass 1: per-chunk in-LDS bin sort, payload staged as 8B/edge
// (key u32 + {fp16 a, fp16 w} u32); sequential reads, dense burst writes.
// key = (row<<16)|col (both < 2^16).
__global__ __launch_bounds__(256) void pass1_kernel(
        const int* __restrict__ row, const int* __restrict__ col,
        const float* __restrict__ a, const float* __restrict__ w,
        const int* __restrict__ hist1_off,
        unsigned* __restrict__ k1, unsigned* __restrict__ aw1) {
    __shared__ int h[NBIN];                  // counts -> placement cursors
    __shared__ int hscan[NBIN];              // block-local exclusive scan
    __shared__ int hoff[NBIN];               // global offsets for (bin, this blk)
    __shared__ int s256[256];
    __shared__ unsigned sKey[CHUNK];         // 24 KB
    __shared__ unsigned sAW[CHUNK];          // 24 KB
    int blk = blockIdx.x, tid = threadIdx.x;
    int base = blk * CHUNK;
    int n = NNZ_E - base; if (n > CHUNK) n = CHUNK;

    for (int j = tid; j < NBIN; j += 256) {
        h[j] = 0;
        hoff[j] = hist1_off[j * NBLK1 + blk];
    }
    __syncthreads();
    for (int i = tid; i < n; i += 256)
        atomicAdd(&h[clampi(row[base + i], NN - 1) >> 7], 1);
    __syncthreads();
    int j0 = tid * 2, j1 = tid * 2 + 1;
    int c0 = (j0 < NBIN) ? h[j0] : 0;
    int c1 = (j1 < NBIN) ? h[j1] : 0;
    int tsum = c0 + c1;
    s256[tid] = tsum;
    __syncthreads();
    for (int off = 1; off < 256; off <<= 1) {
        int t = (tid >= off) ? s256[tid - off] : 0;
        __syncthreads();
        s256[tid] += t;
        __syncthreads();
    }
    int ex = s256[tid] - tsum;
    __syncthreads();
    if (j0 < NBIN) { hscan[j0] = ex;      h[j0] = ex; }
    if (j1 < NBIN) { hscan[j1] = ex + c0; h[j1] = ex + c0; }
    __syncthreads();
    for (int i = tid; i < n; i += 256) {
        int r = clampi(row[base + i], NN - 1);
        int c = clampi(col[base + i], NN - 1);
        int bin = r >> 7;
        int p = atomicAdd(&h[bin], 1);       // LDS cursor, block-private
        p = clampi(p, n - 1);                // hardening
        sKey[p] = ((unsigned)r << 16) | (unsigned)c;
        sAW[p] = ((unsigned)f2h(a[base + i]) << 16) | (unsigned)f2h(w[base + i]);
    }
    __syncthreads();
    for (int p = tid; p < n; p += 256) {
        unsigned key = sKey[p];
        int bin = (int)(key >> 23);          // = row >> 7
        int d = clampi(hoff[bin] + (p - hscan[bin]), NNZ_E - 1);
        k1[d] = key;
        aw1[d] = sAW[p];
    }
}

// Pass 2: one block per 128-row bin. Row hist + padded-length scan in LDS,
// emits row_desc[r] = start | (niters<<24) and writes kvA2/kvW2 into the
// bin's fixed 6144-slot window with per-row multiple-of-8 padding (pad kv=0).
__global__ __launch_bounds__(256) void pass2_kernel(
        const unsigned* __restrict__ k1, const unsigned* __restrict__ aw1,
        const int* __restrict__ binstart,
        unsigned* __restrict__ kvA2, unsigned* __restrict__ kvW2,
        unsigned* __restrict__ row_desc) {
    __shared__ unsigned sKey[CAP2];          // 20 KB
    __shared__ unsigned sAW[CAP2];           // 20 KB
    __shared__ int rh[128];
    __shared__ int rs[128];
    __shared__ int cur[128];
    int bin = blockIdx.x, tid = threadIdx.x;
    int r0 = bin << 7;
    int rows = NN - r0; if (rows > 128) rows = 128;
    int base = clampi(binstart[bin], NNZ_E);
    int size = clampi(binstart[bin + 1], NNZ_E) - base;
    size = clampi(size, CAP2);               // hardening (always fits in practice)
    int pbase = bin * BCAP;

    if (tid < 128) rh[tid] = 0;
    __syncthreads();
    for (int i = tid; i < size; i += 256) {
        unsigned key = k1[base + i];
        atomicAdd(&rh[(key >> 16) & 127], 1);
        sKey[i] = key;
        sAW[i] = aw1[base + i];
    }
    __syncthreads();
    int cnt  = (tid < 128) ? rh[tid] : 0;
    int plen = (cnt + 7) & ~7;
    if (tid < 128) rs[tid] = plen;
    __syncthreads();
    for (int off = 1; off < 128; off <<= 1) {
        int t = (tid >= off && tid < 128) ? rs[tid - off] : 0;
        __syncthreads();
        if (tid < 128) rs[tid] += t;
        __syncthreads();
    }
    int rofs = (tid < 128) ? clampi(rs[tid] - plen, BCAP - 8) : 0;
    if (tid < 128) cur[tid] = rofs;
    if (tid < rows)
        row_desc[r0 + tid] = (unsigned)(pbase + rofs) | ((unsigned)(plen >> 3) << 24);
    __syncthreads();
    for (int i = tid; i < size; i += 256) {
        unsigned key = sKey[i];
        unsigned aw  = sAW[i];
        int rl = (key >> 16) & 127;
        int p = atomicAdd(&cur[rl], 1);
        p = clampi(p, BCAP - 1);             // hardening
        unsigned c = key & 0xFFFFu;
        kvA2[pbase + p] = (aw & 0xFFFF0000u) | c;
        kvW2[pbase + p] = (aw << 16) | c;
    }
    __syncthreads();
    if (tid < rows) {
        int pl = (rh[tid] + 7) & ~7;
        for (int q = rh[tid]; q < pl; ++q) {
            int d = clampi(rofs + q, BCAP - 1);
            kvA2[pbase + d] = 0u;
            kvW2[pbase + d] = 0u;
        }
    }
}

__global__ void transpose_in_kernel(const float* __restrict__ x,
                                    _Float16* __restrict__ xt) {
    int i = blockIdx.x * blockDim.x + threadIdx.x;  // i = n*32 + b
    if (i < NB) {
        int n = i >> 5;
        int b = i & 31;
        xt[i] = (_Float16)x[b * NN + n];
    }
}

// 16 lanes per row; lane l owns batch pair (2l, 2l+1) as one fp16x2 dword.
// 4 rows per wave64. Depth-2 pipeline: kv held TWO iterations ahead (kA=cur,
// kB=next, next-next issued in-loop), so gathers for iter it+1 are issued
// from arrived kv while iter it computes — gather latency hides under
// compute + wave interleave instead of serializing every iteration.
// fp32 accumulation, identical edge order => numerics identical to r15.
// Epilogue: out = acc*outScale + bias[r]*biasScale (scaled-state scheme).
template <int WITH_BIAS>
__global__ __launch_bounds__(256, 8) void spmm_kernel(
        const uint4* __restrict__ kv4, const unsigned* __restrict__ row_desc,
        const unsigned* __restrict__ in32, unsigned* __restrict__ out32,
        const float* __restrict__ bias, float outScale, float biasScale) {
    int t = blockIdx.x * 256 + threadIdx.x;
    int r = t >> 4;                          // one row per 16 lanes
    int l = t & 15;                          // batch-pair index
    if (r >= NN) return;
    unsigned d = row_desc[r];
    int niter = (int)(d >> 24);
    int base4 = clampi((int)(d & 0xFFFFFFu), LENP - 8) >> 2;  // uint4 idx (8-slot aligned)
    const uint4* kp = kv4 + base4;
    float accL = 0.0f, accH = 0.0f;
    uint4 kA0, kA1, kB0, kB1;
    unsigned gC[8], gN[8];
    if (niter > 0) {
        kA0 = kp[0]; kA1 = kp[1];            // kv for iter 0
#pragma unroll
        for (int j = 0; j < 8; ++j) {        // gathers for iter 0
            unsigned kw = u4_at(j < 4 ? kA0 : kA1, j);
            gC[j] = in32[((kw & 0xFFFFu) << 4) + l];
        }
        kB0 = kA0; kB1 = kA1;
        if (niter > 1) { kB0 = kp[2]; kB1 = kp[3]; }   // kv for iter 1
    }
    for (int it = 0; it < niter; ++it) {
        // issue next iteration's gathers from ARRIVED kv (kB)
        if (it + 1 < niter) {
#pragma unroll
            for (int j = 0; j < 8; ++j) {
                unsigned kw = u4_at(j < 4 ? kB0 : kB1, j);
                gN[j] = in32[((kw & 0xFFFFu) << 4) + l];
            }
        }
        // compute current iteration (kA vals x gC); prefetched loads in flight
#pragma unroll
        for (int j = 0; j < 8; ++j) {
            float v = kv_val(u4_at(j < 4 ? kA0 : kA1, j));
            union { unsigned u; _Float16 h[2]; } cv;
            cv.u = gC[j];
            accL += v * (float)cv.h[0];
            accH += v * (float)cv.h[1];
        }
        // shift pipeline: kA <- kB, kB <- kv(it+2), gC <- gN
        kA0 = kB0; kA1 = kB1;
        if (it + 2 < niter) { kB0 = kp[(it + 2) * 2]; kB1 = kp[(it + 2) * 2 + 1]; }
#pragma unroll
        for (int j = 0; j < 8; ++j) gC[j] = gN[j];
    }
    float rL = accL * outScale, rH = accH * outScale;
    if (WITH_BIAS) {
        float bb = bias[r] * biasScale;
        rL += bb; rH += bb;
    }
    union { unsigned u; _Float16 h[2]; } o;
    o.h[0] = (_Float16)rL;
    o.h[1] = (_Float16)rH;
    out32[(r << 4) + l] = o.u;
}

// Final: out = state * 2^24 (undoes the cumulative 256^-3 state scaling).
__global__ void transpose_out_kernel(const _Float16* __restrict__ xt,
                                     float* __restrict__ out) {
    int i = blockIdx.x * blockDim.x + threadIdx.x;  // i = b*N + n (coalesced write)
    if (i < NB) {
        int b = i / NN;
        int n = i - b * NN;
        out[i] = (float)xt[(n << 5) + b] * 16777216.0f;
    }
}

extern "C" void kernel_launch(void* const* d_in, const int* in_sizes, int n_in,
                              void* d_out, int out_size, void* d_ws, size_t ws_size,
                              hipStream_t stream) {
    const float* x        = (const float*)d_in[0];
    const float* adj_vals = (const float*)d_in[1];
    const float* w_vals   = (const float*)d_in[2];
    const float* bias     = (const float*)d_in[3];
    const int*   row      = (const int*)d_in[4];
    const int*   col      = (const int*)d_in[5];
    float* out = (float*)d_out;

    // Workspace (~40 MB of the 256 MiB ws)
    unsigned*  k1        = (unsigned*)d_ws;          // NNZ_E (sort keys)
    unsigned*  aw1       = k1 + NNZ_E;               // NNZ_E (packed fp16 a,w)
    unsigned*  kvA2      = aw1 + NNZ_E;              // LENP padded kv (A)
    unsigned*  kvW2      = kvA2 + LENP;              // LENP padded kv (W)
    _Float16*  xt16      = (_Float16*)(kvW2 + LENP); // NB fp16
    _Float16*  tmp16     = xt16 + NB;                // NB fp16
    int*   hist1         = (int*)(tmp16 + NB);       // NH (scanned in place)
    int*   bsumB         = hist1 + NH;               // 512
    int*   binstart      = bsumB + 512;              // NBIN+1 (+pad)
    unsigned* row_desc   = (unsigned*)(binstart + NBIN + 8);  // NN

    const int BS = 256;
    const int grid_nb   = (NB + BS - 1) / BS;        // 6250
    const int grid_spmm = (NN * 16 + BS - 1) / BS;   // 3125

    // ---- (chunk,bin) histogram matrix + bin-major scan ----
    hist_kernel<<<NBLK1, BS, 0, stream>>>(row, hist1);
    scan_local_kernel<<<SCAN_NBLK, BS, 0, stream>>>(hist1, NH, bsumB);
    scan_tops_kernel<<<1, 512, 0, stream>>>(bsumB, SCAN_NBLK);
    fin_add_kernel<<<SCAN_NBLK, BS, 0, stream>>>(hist1, NH, bsumB);
    binstart_kernel<<<(NBIN + 1 + BS - 1) / BS, BS, 0, stream>>>(hist1, binstart);

    // ---- two-pass sort: bin-group then padded per-row placement ----
    pass1_kernel<<<NBLK1, BS, 0, stream>>>(row, col, adj_vals, w_vals,
                                           hist1, k1, aw1);
    pass2_kernel<<<NBIN, BS, 0, stream>>>(k1, aw1, binstart, kvA2, kvW2, row_desc);

    const uint4* kvA = (const uint4*)kvA2;
    const uint4* kvW = (const uint4*)kvW2;
    const unsigned* xt32  = (const unsigned*)xt16;
    unsigned*       xt32w = (unsigned*)xt16;
    const unsigned* tm32  = (const unsigned*)tmp16;
    unsigned*       tm32w = (unsigned*)tmp16;

    // ---- dense passes (scaled fp16 state: state_l = xt_l * 256^-l) ----
    transpose_in_kernel<<<grid_nb, BS, 0, stream>>>(x, xt16);
    const float r256 = 1.0f / 256.0f;
    float biasScale = 1.0f;
    for (int layer = 0; layer < 3; ++layer) {
        biasScale *= r256;                   // 256^-(layer+1)
        spmm_kernel<0><<<grid_spmm, BS, 0, stream>>>(kvW, row_desc, xt32, tm32w,
                                                     nullptr, 1.0f, 0.0f);
        spmm_kernel<1><<<grid_spmm, BS, 0, stream>>>(kvA, row_desc, tm32, xt32w,
                                                     bias, r256, biasScale);
    }
    transpose_out_kernel<<<grid_nb, BS, 0, stream>>>(xt16, out);
}

// Round 4
// 241.654 us; speedup vs baseline: 1.0846x; 1.0846x over previous
//
#include <hip/hip_runtime.h>

// AdultConnectomeNetwork: 3 layers of xt = A_sp @ (W_sp @ xt) + bias.
// Round 19: dispatch-count reduction (16 -> 11). r17/r18 showed spmm
// microstructure changes move total by only +-15us => kernels are small and
// ~150us is dispatch/launch overhead of 16 serially-dependent dispatches.
//  - spmm reverted to EXACT r15 form (best measured: 247us): 16 lanes/row,
//    fp16x2 batch pairs, uint2 kv loads, depth-1 kv prefetch.
//  - transpose_in fused into hist_kernel (independent work, extra blocks).
//  - scan_tops+fin_add+binstart fused into one scanfin_kernel (each block
//    re-scans the 399 block-sums in LDS ping-pong, adds, emits binstart).
//  - transpose_out fused into the final A-pass spmm (direct fp32 out writes,
//    skips intermediate fp16 rounding => numerics equal or better).
//  - Scaled fp16 state: state_l = xt_l*256^-l, exact pow2 rescale in
//    epilogues, x2^24 at the end (round 13; overflow-proof).
//  - Sort: two-pass LDS-staged counting sort (rounds 9-13), unchanged.
// Hardening: computed indices clamped (logic error -> absmax fail, not fault).

#define NN 50000
#define NNZ_E 1600000
#define NB (NN * 32)
#define CHUNK 6144
#define NBLK1 ((NNZ_E + CHUNK - 1) / CHUNK)      // 261
#define NBIN ((NN + 127) / 128)                  // 391 bins of 128 rows
#define NH (NBIN * NBLK1)                        // 102051
#define CAP2 5120                                // bin window cap (mean 4092, +16 sigma)
#define BCAP 6144                                // padded per-bin capacity
#define LENP (NBIN * BCAP)                       // 2402304 padded slots
#define SCAN_NBLK ((NH + 255) / 256)             // 399
#define TIN_BLKS 98                              // transpose-in blocks fused into hist

__device__ __forceinline__ int clampi(int v, int hi) {  // [0, hi]
    v = v < 0 ? 0 : v;
    return v > hi ? hi : v;
}

__device__ __forceinline__ unsigned short f2h(float v) {
    union { _Float16 h; unsigned short u; } cv;
    cv.h = (_Float16)v;
    return cv.u;
}

__device__ __forceinline__ float kv_val(unsigned kv) {
    union { unsigned short u; _Float16 h; } cv;
    cv.u = (unsigned short)(kv >> 16);
    return (float)cv.h;
}

// Per-(chunk,bin) histogram matrix, bin-major. LDS only, no global atomics.
// Blocks >= NBLK1 instead run the input transpose (fp32 [B,N] -> fp16 [N,32]);
// xt16 is not consumed until the first spmm, well after this dispatch.
__global__ __launch_bounds__(256) void hist_kernel(const int* __restrict__ row,
                                                   int* __restrict__ hist1,
                                                   const float* __restrict__ x,
                                                   _Float16* __restrict__ xt) {
    __shared__ int h[NBIN];
    int blk = blockIdx.x, tid = threadIdx.x;
    if (blk >= NBLK1) {                      // fused transpose_in
        for (int i = (blk - NBLK1) * 256 + tid; i < NB; i += TIN_BLKS * 256) {
            int n = i >> 5;
            int b = i & 31;
            xt[i] = (_Float16)x[b * NN + n];
        }
        return;
    }
    for (int j = tid; j < NBIN; j += 256) h[j] = 0;
    __syncthreads();
    int base = blk * CHUNK;
    int n = NNZ_E - base; if (n > CHUNK) n = CHUNK;
    for (int i = tid; i < n; i += 256)
        atomicAdd(&h[clampi(row[base + i], NN - 1) >> 7], 1);
    __syncthreads();
    for (int j = tid; j < NBIN; j += 256) hist1[j * NBLK1 + blk] = h[j];
}

// Exclusive scan within 256-blocks; bsum[blk] = block total.
__global__ void scan_local_kernel(int* __restrict__ data, int n, int* __restrict__ bsum) {
    __shared__ int s[256];
    int i = blockIdx.x * 256 + threadIdx.x;
    int v = (i < n) ? data[i] : 0;
    s[threadIdx.x] = v;
    __syncthreads();
    for (int off = 1; off < 256; off <<= 1) {
        int t = (threadIdx.x >= off) ? s[threadIdx.x - off] : 0;
        __syncthreads();
        s[threadIdx.x] += t;
        __syncthreads();
    }
    if (i < n) data[i] = s[threadIdx.x] - v;     // exclusive within block
    if (threadIdx.x == 255) bsum[blockIdx.x] = s[threadIdx.x];
}

// Fused scan_tops + fin_add + binstart. Every block loads all SCAN_NBLK block
// sums into LDS, scans them (ping-pong Hillis-Steele over 512 slots), adds
// the exclusive prefix for its own block to its 256 elements, and emits
// binstart inline (binstart[j] = final hist1[j*NBLK1]).
__global__ __launch_bounds__(256) void scanfin_kernel(int* __restrict__ data, int n,
                                                      const int* __restrict__ bsum, int m,
                                                      int* __restrict__ binstart) {
    __shared__ int sa[512];
    __shared__ int sb[512];
    int tid = threadIdx.x;
    sa[tid]       = (tid < m) ? bsum[tid] : 0;
    sa[tid + 256] = (tid + 256 < m) ? bsum[tid + 256] : 0;
    __syncthreads();
    int* src = sa;
    int* dst = sb;
    for (int off = 1; off < 512; off <<= 1) {
#pragma unroll
        for (int q = 0; q < 2; ++q) {
            int p = tid + q * 256;
            int v = src[p];
            if (p >= off) v += src[p - off];
            dst[p] = v;
        }
        __syncthreads();
        int* t = src; src = dst; dst = t;
    }
    // src = inclusive scan of bsum
    int add = (blockIdx.x > 0) ? src[blockIdx.x - 1] : 0;
    int i = blockIdx.x * 256 + tid;
    if (i < n) {
        int v = data[i] + add;
        data[i] = v;
        if (i % NBLK1 == 0) binstart[i / NBLK1] = v;   // i = j*NBLK1, j < NBIN
    }
    if (i == 0) binstart[NBIN] = NNZ_E;
}

// Pass 1: per-chunk in-LDS bin sort, payload staged as 8B/edge
// (key u32 + {fp16 a, fp16 w} u32); sequential reads, dense burst writes.
// key = (row<<16)|col (both < 2^16).
__global__ __launch_bounds__(256) void pass1_kernel(
        const int* __restrict__ row, const int* __restrict__ col,
        const float* __restrict__ a, const float* __restrict__ w,
        const int* __restrict__ hist1_off,
        unsigned* __restrict__ k1, unsigned* __restrict__ aw1) {
    __shared__ int h[NBIN];                  // counts -> placement cursors
    __shared__ int hscan[NBIN];              // block-local exclusive scan
    __shared__ int hoff[NBIN];               // global offsets for (bin, this blk)
    __shared__ int s256[256];
    __shared__ unsigned sKey[CHUNK];         // 24 KB
    __shared__ unsigned sAW[CHUNK];          // 24 KB
    int blk = blockIdx.x, tid = threadIdx.x;
    int base = blk * CHUNK;
    int n = NNZ_E - base; if (n > CHUNK) n = CHUNK;

    for (int j = tid; j < NBIN; j += 256) {
        h[j] = 0;
        hoff[j] = hist1_off[j * NBLK1 + blk];
    }
    __syncthreads();
    for (int i = tid; i < n; i += 256)
        atomicAdd(&h[clampi(row[base + i], NN - 1) >> 7], 1);
    __syncthreads();
    int j0 = tid * 2, j1 = tid * 2 + 1;
    int c0 = (j0 < NBIN) ? h[j0] : 0;
    int c1 = (j1 < NBIN) ? h[j1] : 0;
    int tsum = c0 + c1;
    s256[tid] = tsum;
    __syncthreads();
    for (int off = 1; off < 256; off <<= 1) {
        int t = (tid >= off) ? s256[tid - off] : 0;
        __syncthreads();
        s256[tid] += t;
        __syncthreads();
    }
    int ex = s256[tid] - tsum;
    __syncthreads();
    if (j0 < NBIN) { hscan[j0] = ex;      h[j0] = ex; }
    if (j1 < NBIN) { hscan[j1] = ex + c0; h[j1] = ex + c0; }
    __syncthreads();
    for (int i = tid; i < n; i += 256) {
        int r = clampi(row[base + i], NN - 1);
        int c = clampi(col[base + i], NN - 1);
        int bin = r >> 7;
        int p = atomicAdd(&h[bin], 1);       // LDS cursor, block-private
        p = clampi(p, n - 1);                // hardening
        sKey[p] = ((unsigned)r << 16) | (unsigned)c;
        sAW[p] = ((unsigned)f2h(a[base + i]) << 16) | (unsigned)f2h(w[base + i]);
    }
    __syncthreads();
    for (int p = tid; p < n; p += 256) {
        unsigned key = sKey[p];
        int bin = (int)(key >> 23);          // = row >> 7
        int d = clampi(hoff[bin] + (p - hscan[bin]), NNZ_E - 1);
        k1[d] = key;
        aw1[d] = sAW[p];
    }
}

// Pass 2: one block per 128-row bin. Row hist + padded-length scan in LDS,
// emits row_desc[r] = start | (niters<<24) and writes kvA2/kvW2 into the
// bin's fixed 6144-slot window with per-row multiple-of-8 padding (pad kv=0).
__global__ __launch_bounds__(256) void pass2_kernel(
        const unsigned* __restrict__ k1, const unsigned* __restrict__ aw1,
        const int* __restrict__ binstart,
        unsigned* __restrict__ kvA2, unsigned* __restrict__ kvW2,
        unsigned* __restrict__ row_desc) {
    __shared__ unsigned sKey[CAP2];          // 20 KB
    __shared__ unsigned sAW[CAP2];           // 20 KB
    __shared__ int rh[128];
    __shared__ int rs[128];
    __shared__ int cur[128];
    int bin = blockIdx.x, tid = threadIdx.x;
    int r0 = bin << 7;
    int rows = NN - r0; if (rows > 128) rows = 128;
    int base = clampi(binstart[bin], NNZ_E);
    int size = clampi(binstart[bin + 1], NNZ_E) - base;
    size = clampi(size, CAP2);               // hardening (always fits in practice)
    int pbase = bin * BCAP;

    if (tid < 128) rh[tid] = 0;
    __syncthreads();
    for (int i = tid; i < size; i += 256) {
        unsigned key = k1[base + i];
        atomicAdd(&rh[(key >> 16) & 127], 1);
        sKey[i] = key;
        sAW[i] = aw1[base + i];
    }
    __syncthreads();
    int cnt  = (tid < 128) ? rh[tid] : 0;
    int plen = (cnt + 7) & ~7;
    if (tid < 128) rs[tid] = plen;
    __syncthreads();
    for (int off = 1; off < 128; off <<= 1) {
        int t = (tid >= off && tid < 128) ? rs[tid - off] : 0;
        __syncthreads();
        if (tid < 128) rs[tid] += t;
        __syncthreads();
    }
    int rofs = (tid < 128) ? clampi(rs[tid] - plen, BCAP - 8) : 0;
    if (tid < 128) cur[tid] = rofs;
    if (tid < rows)
        row_desc[r0 + tid] = (unsigned)(pbase + rofs) | ((unsigned)(plen >> 3) << 24);
    __syncthreads();
    for (int i = tid; i < size; i += 256) {
        unsigned key = sKey[i];
        unsigned aw  = sAW[i];
        int rl = (key >> 16) & 127;
        int p = atomicAdd(&cur[rl], 1);
        p = clampi(p, BCAP - 1);             // hardening
        unsigned c = key & 0xFFFFu;
        kvA2[pbase + p] = (aw & 0xFFFF0000u) | c;
        kvW2[pbase + p] = (aw << 16) | c;
    }
    __syncthreads();
    if (tid < rows) {
        int pl = (rh[tid] + 7) & ~7;
        for (int q = rh[tid]; q < pl; ++q) {
            int d = clampi(rofs + q, BCAP - 1);
            kvA2[pbase + d] = 0u;
            kvW2[pbase + d] = 0u;
        }
    }
}

// 16 lanes per row; lane l owns batch pair (2l, 2l+1) as one fp16x2 dword.
// 4 rows per wave64 (exact r15 structure: uniform counted loop over rows
// padded to multiple-of-8 edges, uint2 kv loads, depth-1 kv prefetch, fp32
// accumulation, packed dword store).
// FINAL=1 (last A-pass): writes fp32 out[b*NN+r] = result * 2^24 directly
// (fused transpose_out; skips the intermediate fp16 rounding).
template <int WITH_BIAS, int FINAL>
__global__ __launch_bounds__(256) void spmm_kernel(
        const uint2* __restrict__ kv2, const unsigned* __restrict__ row_desc,
        const unsigned* __restrict__ in32, unsigned* __restrict__ out32,
        const float* __restrict__ bias, float outScale, float biasScale,
        float* __restrict__ outf) {
    int t = blockIdx.x * 256 + threadIdx.x;
    int r = t >> 4;                          // one row per 16 lanes
    int l = t & 15;                          // batch-pair index
    if (r >= NN) return;
    unsigned d = row_desc[r];
    int niter = (int)(d >> 24);
    int base2 = clampi((int)(d & 0xFFFFFFu), LENP - 8) >> 1;  // 8-slot aligned
    float accL = 0.0f, accH = 0.0f;          // batch 2l, 2l+1
    uint2 k2[4];
    if (niter > 0) {
#pragma unroll
        for (int q = 0; q < 4; ++q) k2[q] = kv2[base2 + q];
    }
    for (int it = 0; it < niter; ++it) {
        unsigned k[8];
#pragma unroll
        for (int q = 0; q < 4; ++q) { k[2 * q] = k2[q].x; k[2 * q + 1] = k2[q].y; }
        unsigned gd[8];
#pragma unroll
        for (int j = 0; j < 8; ++j) gd[j] = in32[((k[j] & 0xFFFFu) << 4) + l];
        if (it + 1 < niter) {
            int nb2 = base2 + (it + 1) * 4;
#pragma unroll
            for (int q = 0; q < 4; ++q) k2[q] = kv2[nb2 + q];
        }
#pragma unroll
        for (int j = 0; j < 8; ++j) {
            float v = kv_val(k[j]);
            union { unsigned u; _Float16 h[2]; } cv;
            cv.u = gd[j];
            accL += v * (float)cv.h[0];
            accH += v * (float)cv.h[1];
        }
    }
    float rL = accL * outScale, rH = accH * outScale;
    if (WITH_BIAS) {
        float bb = bias[r] * biasScale;
        rL += bb; rH += bb;
    }
    if (FINAL) {
        // fused transpose_out: undo cumulative 256^-3 state scaling (x 2^24)
        outf[(2 * l) * NN + r]     = rL * 16777216.0f;
        outf[(2 * l + 1) * NN + r] = rH * 16777216.0f;
    } else {
        union { unsigned u; _Float16 h[2]; } o;
        o.h[0] = (_Float16)rL;
        o.h[1] = (_Float16)rH;
        out32[(r << 4) + l] = o.u;
    }
}

extern "C" void kernel_launch(void* const* d_in, const int* in_sizes, int n_in,
                              void* d_out, int out_size, void* d_ws, size_t ws_size,
                              hipStream_t stream) {
    const float* x        = (const float*)d_in[0];
    const float* adj_vals = (const float*)d_in[1];
    const float* w_vals   = (const float*)d_in[2];
    const float* bias     = (const float*)d_in[3];
    const int*   row      = (const int*)d_in[4];
    const int*   col      = (const int*)d_in[5];
    float* out = (float*)d_out;

    // Workspace (~40 MB of the 256 MiB ws)
    unsigned*  k1        = (unsigned*)d_ws;          // NNZ_E (sort keys)
    unsigned*  aw1       = k1 + NNZ_E;               // NNZ_E (packed fp16 a,w)
    unsigned*  kvA2      = aw1 + NNZ_E;              // LENP padded kv (A)
    unsigned*  kvW2      = kvA2 + LENP;              // LENP padded kv (W)
    _Float16*  xt16      = (_Float16*)(kvW2 + LENP); // NB fp16
    _Float16*  tmp16     = xt16 + NB;                // NB fp16
    int*   hist1         = (int*)(tmp16 + NB);       // NH (scanned in place)
    int*   bsumB         = hist1 + NH;               // 512
    int*   binstart      = bsumB + 512;              // NBIN+1 (+pad)
    unsigned* row_desc   = (unsigned*)(binstart + NBIN + 8);  // NN

    const int BS = 256;
    const int grid_spmm = (NN * 16 + BS - 1) / BS;   // 3125

    // ---- (chunk,bin) histogram (+fused input transpose) + bin-major scan ----
    hist_kernel<<<NBLK1 + TIN_BLKS, BS, 0, stream>>>(row, hist1, x, xt16);
    scan_local_kernel<<<SCAN_NBLK, BS, 0, stream>>>(hist1, NH, bsumB);
    scanfin_kernel<<<SCAN_NBLK, BS, 0, stream>>>(hist1, NH, bsumB, SCAN_NBLK, binstart);

    // ---- two-pass sort: bin-group then padded per-row placement ----
    pass1_kernel<<<NBLK1, BS, 0, stream>>>(row, col, adj_vals, w_vals,
                                           hist1, k1, aw1);
    pass2_kernel<<<NBIN, BS, 0, stream>>>(k1, aw1, binstart, kvA2, kvW2, row_desc);

    const uint2* kvA = (const uint2*)kvA2;
    const uint2* kvW = (const uint2*)kvW2;
    const unsigned* xt32  = (const unsigned*)xt16;
    unsigned*       xt32w = (unsigned*)xt16;
    const unsigned* tm32  = (const unsigned*)tmp16;
    unsigned*       tm32w = (unsigned*)tmp16;

    // ---- dense passes (scaled fp16 state: state_l = xt_l * 256^-l) ----
    const float r256 = 1.0f / 256.0f;
    spmm_kernel<0, 0><<<grid_spmm, BS, 0, stream>>>(kvW, row_desc, xt32, tm32w,
                                                    nullptr, 1.0f, 0.0f, nullptr);
    spmm_kernel<1, 0><<<grid_spmm, BS, 0, stream>>>(kvA, row_desc, tm32, xt32w,
                                                    bias, r256, 1.0f / 256.0f, nullptr);
    spmm_kernel<0, 0><<<grid_spmm, BS, 0, stream>>>(kvW, row_desc, xt32, tm32w,
                                                    nullptr, 1.0f, 0.0f, nullptr);
    spmm_kernel<1, 0><<<grid_spmm, BS, 0, stream>>>(kvA, row_desc, tm32, xt32w,
                                                    bias, r256, 1.0f / 65536.0f, nullptr);
    spmm_kernel<0, 0><<<grid_spmm, BS, 0, stream>>>(kvW, row_desc, xt32, tm32w,
                                                    nullptr, 1.0f, 0.0f, nullptr);
    spmm_kernel<1, 1><<<grid_spmm, BS, 0, stream>>>(kvA, row_desc, tm32, xt32w,
                                                    bias, r256, 1.0f / 16777216.0f, out);
}

// Round 5
// 241.200 us; speedup vs baseline: 1.0867x; 1.0019x over previous
//
#include <hip/hip_runtime.h>

// AdultConnectomeNetwork: 3 layers of xt = A_sp @ (W_sp @ xt) + bias.
// Round 20: sort-chain parallelism. rocprof r19: pass1_kernel = 44us with
// OccupancyPercent 6.2 / VALUBusy 2.6 / 754 GB/s for 33MB -> latency-starved
// (55KB LDS => 2 blocks/CU cap; 261 blocks => ~1 resident block/CU).
//  - CHUNK 6144 -> 3072: pass1 LDS 48->24KB (total ~30KB => 5 blocks/CU by
//    LDS and VGPR), grid 261 -> 521 blocks. ~5x more latency hiding.
//  - scanfin widened to 1024-slot LDS scan (SCAN_NBLK 399 -> 796).
//  - Sorted order unchanged (chunk-major within bin, finer chunks) => dense
//    passes see identical kv streams; numerics bit-identical to r19.
//  - Everything else unchanged from r19 (11 dispatches, fused transposes,
//    r15 spmm form, scaled fp16 state).
// Hardening: computed indices clamped (logic error -> absmax fail, not fault).

#define NN 50000
#define NNZ_E 1600000
#define NB (NN * 32)
#define CHUNK 3072
#define NBLK1 ((NNZ_E + CHUNK - 1) / CHUNK)      // 521
#define NBIN ((NN + 127) / 128)                  // 391 bins of 128 rows
#define NH (NBIN * NBLK1)                        // 203711
#define CAP2 5120                                // bin window cap (mean 4092, +16 sigma)
#define BCAP 6144                                // padded per-bin capacity
#define LENP (NBIN * BCAP)                       // 2402304 padded slots
#define SCAN_NBLK ((NH + 255) / 256)             // 796
#define TIN_BLKS 98                              // transpose-in blocks fused into hist

__device__ __forceinline__ int clampi(int v, int hi) {  // [0, hi]
    v = v < 0 ? 0 : v;
    return v > hi ? hi : v;
}

__device__ __forceinline__ unsigned short f2h(float v) {
    union { _Float16 h; unsigned short u; } cv;
    cv.h = (_Float16)v;
    return cv.u;
}

__device__ __forceinline__ float kv_val(unsigned kv) {
    union { unsigned short u; _Float16 h; } cv;
    cv.u = (unsigned short)(kv >> 16);
    return (float)cv.h;
}

// Per-(chunk,bin) histogram matrix, bin-major. LDS only, no global atomics.
// Blocks >= NBLK1 instead run the input transpose (fp32 [B,N] -> fp16 [N,32]);
// xt16 is not consumed until the first spmm, well after this dispatch.
__global__ __launch_bounds__(256) void hist_kernel(const int* __restrict__ row,
                                                   int* __restrict__ hist1,
                                                   const float* __restrict__ x,
                                                   _Float16* __restrict__ xt) {
    __shared__ int h[NBIN];
    int blk = blockIdx.x, tid = threadIdx.x;
    if (blk >= NBLK1) {                      // fused transpose_in
        for (int i = (blk - NBLK1) * 256 + tid; i < NB; i += TIN_BLKS * 256) {
            int n = i >> 5;
            int b = i & 31;
            xt[i] = (_Float16)x[b * NN + n];
        }
        return;
    }
    for (int j = tid; j < NBIN; j += 256) h[j] = 0;
    __syncthreads();
    int base = blk * CHUNK;
    int n = NNZ_E - base; if (n > CHUNK) n = CHUNK;
    for (int i = tid; i < n; i += 256)
        atomicAdd(&h[clampi(row[base + i], NN - 1) >> 7], 1);
    __syncthreads();
    for (int j = tid; j < NBIN; j += 256) hist1[j * NBLK1 + blk] = h[j];
}

// Exclusive scan within 256-blocks; bsum[blk] = block total.
__global__ void scan_local_kernel(int* __restrict__ data, int n, int* __restrict__ bsum) {
    __shared__ int s[256];
    int i = blockIdx.x * 256 + threadIdx.x;
    int v = (i < n) ? data[i] : 0;
    s[threadIdx.x] = v;
    __syncthreads();
    for (int off = 1; off < 256; off <<= 1) {
        int t = (threadIdx.x >= off) ? s[threadIdx.x - off] : 0;
        __syncthreads();
        s[threadIdx.x] += t;
        __syncthreads();
    }
    if (i < n) data[i] = s[threadIdx.x] - v;     // exclusive within block
    if (threadIdx.x == 255) bsum[blockIdx.x] = s[threadIdx.x];
}

// Fused scan_tops + fin_add + binstart. Every block loads all SCAN_NBLK block
// sums into LDS (1024 slots, 4/thread), scans them (ping-pong Hillis-Steele),
// adds the exclusive prefix for its own block to its 256 elements, and emits
// binstart inline (binstart[j] = final hist1[j*NBLK1]).
__global__ __launch_bounds__(256) void scanfin_kernel(int* __restrict__ data, int n,
                                                      const int* __restrict__ bsum, int m,
                                                      int* __restrict__ binstart) {
    __shared__ int sa[1024];
    __shared__ int sb[1024];
    int tid = threadIdx.x;
#pragma unroll
    for (int q = 0; q < 4; ++q) {
        int p = tid + q * 256;
        sa[p] = (p < m) ? bsum[p] : 0;
    }
    __syncthreads();
    int* src = sa;
    int* dst = sb;
    for (int off = 1; off < 1024; off <<= 1) {
#pragma unroll
        for (int q = 0; q < 4; ++q) {
            int p = tid + q * 256;
            int v = src[p];
            if (p >= off) v += src[p - off];
            dst[p] = v;
        }
        __syncthreads();
        int* t = src; src = dst; dst = t;
    }
    // src = inclusive scan of bsum
    int add = (blockIdx.x > 0) ? src[blockIdx.x - 1] : 0;
    int i = blockIdx.x * 256 + tid;
    if (i < n) {
        int v = data[i] + add;
        data[i] = v;
        if (i % NBLK1 == 0) binstart[i / NBLK1] = v;   // i = j*NBLK1, j < NBIN
    }
    if (i == 0) binstart[NBIN] = NNZ_E;
}

// Pass 1: per-chunk in-LDS bin sort, payload staged as 8B/edge
// (key u32 + {fp16 a, fp16 w} u32); sequential reads, dense burst writes.
// key = (row<<16)|col (both < 2^16).
__global__ __launch_bounds__(256) void pass1_kernel(
        const int* __restrict__ row, const int* __restrict__ col,
        const float* __restrict__ a, const float* __restrict__ w,
        const int* __restrict__ hist1_off,
        unsigned* __restrict__ k1, unsigned* __restrict__ aw1) {
    __shared__ int h[NBIN];                  // counts -> placement cursors
    __shared__ int hscan[NBIN];              // block-local exclusive scan
    __shared__ int hoff[NBIN];               // global offsets for (bin, this blk)
    __shared__ int s256[256];
    __shared__ unsigned sKey[CHUNK];         // 12 KB
    __shared__ unsigned sAW[CHUNK];          // 12 KB
    int blk = blockIdx.x, tid = threadIdx.x;
    int base = blk * CHUNK;
    int n = NNZ_E - base; if (n > CHUNK) n = CHUNK;

    for (int j = tid; j < NBIN; j += 256) {
        h[j] = 0;
        hoff[j] = hist1_off[j * NBLK1 + blk];
    }
    __syncthreads();
    for (int i = tid; i < n; i += 256)
        atomicAdd(&h[clampi(row[base + i], NN - 1) >> 7], 1);
    __syncthreads();
    int j0 = tid * 2, j1 = tid * 2 + 1;
    int c0 = (j0 < NBIN) ? h[j0] : 0;
    int c1 = (j1 < NBIN) ? h[j1] : 0;
    int tsum = c0 + c1;
    s256[tid] = tsum;
    __syncthreads();
    for (int off = 1; off < 256; off <<= 1) {
        int t = (tid >= off) ? s256[tid - off] : 0;
        __syncthreads();
        s256[tid] += t;
        __syncthreads();
    }
    int ex = s256[tid] - tsum;
    __syncthreads();
    if (j0 < NBIN) { hscan[j0] = ex;      h[j0] = ex; }
    if (j1 < NBIN) { hscan[j1] = ex + c0; h[j1] = ex + c0; }
    __syncthreads();
    for (int i = tid; i < n; i += 256) {
        int r = clampi(row[base + i], NN - 1);
        int c = clampi(col[base + i], NN - 1);
        int bin = r >> 7;
        int p = atomicAdd(&h[bin], 1);       // LDS cursor, block-private
        p = clampi(p, n - 1);                // hardening
        sKey[p] = ((unsigned)r << 16) | (unsigned)c;
        sAW[p] = ((unsigned)f2h(a[base + i]) << 16) | (unsigned)f2h(w[base + i]);
    }
    __syncthreads();
    for (int p = tid; p < n; p += 256) {
        unsigned key = sKey[p];
        int bin = (int)(key >> 23);          // = row >> 7
        int d = clampi(hoff[bin] + (p - hscan[bin]), NNZ_E - 1);
        k1[d] = key;
        aw1[d] = sAW[p];
    }
}

// Pass 2: one block per 128-row bin. Row hist + padded-length scan in LDS,
// emits row_desc[r] = start | (niters<<24) and writes kvA2/kvW2 into the
// bin's fixed 6144-slot window with per-row multiple-of-8 padding (pad kv=0).
__global__ __launch_bounds__(256) void pass2_kernel(
        const unsigned* __restrict__ k1, const unsigned* __restrict__ aw1,
        const int* __restrict__ binstart,
        unsigned* __restrict__ kvA2, unsigned* __restrict__ kvW2,
        unsigned* __restrict__ row_desc) {
    __shared__ unsigned sKey[CAP2];          // 20 KB
    __shared__ unsigned sAW[CAP2];           // 20 KB
    __shared__ int rh[128];
    __shared__ int rs[128];
    __shared__ int cur[128];
    int bin = blockIdx.x, tid = threadIdx.x;
    int r0 = bin << 7;
    int rows = NN - r0; if (rows > 128) rows = 128;
    int base = clampi(binstart[bin], NNZ_E);
    int size = clampi(binstart[bin + 1], NNZ_E) - base;
    size = clampi(size, CAP2);               // hardening (always fits in practice)
    int pbase = bin * BCAP;

    if (tid < 128) rh[tid] = 0;
    __syncthreads();
    for (int i = tid; i < size; i += 256) {
        unsigned key = k1[base + i];
        atomicAdd(&rh[(key >> 16) & 127], 1);
        sKey[i] = key;
        sAW[i] = aw1[base + i];
    }
    __syncthreads();
    int cnt  = (tid < 128) ? rh[tid] : 0;
    int plen = (cnt + 7) & ~7;
    if (tid < 128) rs[tid] = plen;
    __syncthreads();
    for (int off = 1; off < 128; off <<= 1) {
        int t = (tid >= off && tid < 128) ? rs[tid - off] : 0;
        __syncthreads();
        if (tid < 128) rs[tid] += t;
        __syncthreads();
    }
    int rofs = (tid < 128) ? clampi(rs[tid] - plen, BCAP - 8) : 0;
    if (tid < 128) cur[tid] = rofs;
    if (tid < rows)
        row_desc[r0 + tid] = (unsigned)(pbase + rofs) | ((unsigned)(plen >> 3) << 24);
    __syncthreads();
    for (int i = tid; i < size; i += 256) {
        unsigned key = sKey[i];
        unsigned aw  = sAW[i];
        int rl = (key >> 16) & 127;
        int p = atomicAdd(&cur[rl], 1);
        p = clampi(p, BCAP - 1);             // hardening
        unsigned c = key & 0xFFFFu;
        kvA2[pbase + p] = (aw & 0xFFFF0000u) | c;
        kvW2[pbase + p] = (aw << 16) | c;
    }
    __syncthreads();
    if (tid < rows) {
        int pl = (rh[tid] + 7) & ~7;
        for (int q = rh[tid]; q < pl; ++q) {
            int d = clampi(rofs + q, BCAP - 1);
            kvA2[pbase + d] = 0u;
            kvW2[pbase + d] = 0u;
        }
    }
}

// 16 lanes per row; lane l owns batch pair (2l, 2l+1) as one fp16x2 dword.
// 4 rows per wave64 (exact r15 structure: uniform counted loop over rows
// padded to multiple-of-8 edges, uint2 kv loads, depth-1 kv prefetch, fp32
// accumulation, packed dword store).
// FINAL=1 (last A-pass): writes fp32 out[b*NN+r] = result * 2^24 directly
// (fused transpose_out; skips the intermediate fp16 rounding).
template <int WITH_BIAS, int FINAL>
__global__ __launch_bounds__(256) void spmm_kernel(
        const uint2* __restrict__ kv2, const unsigned* __restrict__ row_desc,
        const unsigned* __restrict__ in32, unsigned* __restrict__ out32,
        const float* __restrict__ bias, float outScale, float biasScale,
        float* __restrict__ outf) {
    int t = blockIdx.x * 256 + threadIdx.x;
    int r = t >> 4;                          // one row per 16 lanes
    int l = t & 15;                          // batch-pair index
    if (r >= NN) return;
    unsigned d = row_desc[r];
    int niter = (int)(d >> 24);
    int base2 = clampi((int)(d & 0xFFFFFFu), LENP - 8) >> 1;  // 8-slot aligned
    float accL = 0.0f, accH = 0.0f;          // batch 2l, 2l+1
    uint2 k2[4];
    if (niter > 0) {
#pragma unroll
        for (int q = 0; q < 4; ++q) k2[q] = kv2[base2 + q];
    }
    for (int it = 0; it < niter; ++it) {
        unsigned k[8];
#pragma unroll
        for (int q = 0; q < 4; ++q) { k[2 * q] = k2[q].x; k[2 * q + 1] = k2[q].y; }
        unsigned gd[8];
#pragma unroll
        for (int j = 0; j < 8; ++j) gd[j] = in32[((k[j] & 0xFFFFu) << 4) + l];
        if (it + 1 < niter) {
            int nb2 = base2 + (it + 1) * 4;
#pragma unroll
            for (int q = 0; q < 4; ++q) k2[q] = kv2[nb2 + q];
        }
#pragma unroll
        for (int j = 0; j < 8; ++j) {
            float v = kv_val(k[j]);
            union { unsigned u; _Float16 h[2]; } cv;
            cv.u = gd[j];
            accL += v * (float)cv.h[0];
            accH += v * (float)cv.h[1];
        }
    }
    float rL = accL * outScale, rH = accH * outScale;
    if (WITH_BIAS) {
        float bb = bias[r] * biasScale;
        rL += bb; rH += bb;
    }
    if (FINAL) {
        // fused transpose_out: undo cumulative 256^-3 state scaling (x 2^24)
        outf[(2 * l) * NN + r]     = rL * 16777216.0f;
        outf[(2 * l + 1) * NN + r] = rH * 16777216.0f;
    } else {
        union { unsigned u; _Float16 h[2]; } o;
        o.h[0] = (_Float16)rL;
        o.h[1] = (_Float16)rH;
        out32[(r << 4) + l] = o.u;
    }
}

extern "C" void kernel_launch(void* const* d_in, const int* in_sizes, int n_in,
                              void* d_out, int out_size, void* d_ws, size_t ws_size,
                              hipStream_t stream) {
    const float* x        = (const float*)d_in[0];
    const float* adj_vals = (const float*)d_in[1];
    const float* w_vals   = (const float*)d_in[2];
    const float* bias     = (const float*)d_in[3];
    const int*   row      = (const int*)d_in[4];
    const int*   col      = (const int*)d_in[5];
    float* out = (float*)d_out;

    // Workspace (~45 MB of the 256 MiB ws)
    unsigned*  k1        = (unsigned*)d_ws;          // NNZ_E (sort keys)
    unsigned*  aw1       = k1 + NNZ_E;               // NNZ_E (packed fp16 a,w)
    unsigned*  kvA2      = aw1 + NNZ_E;              // LENP padded kv (A)
    unsigned*  kvW2      = kvA2 + LENP;              // LENP padded kv (W)
    _Float16*  xt16      = (_Float16*)(kvW2 + LENP); // NB fp16
    _Float16*  tmp16     = xt16 + NB;                // NB fp16
    int*   hist1         = (int*)(tmp16 + NB);       // NH (scanned in place)
    int*   bsumB         = hist1 + NH;               // 1024
    int*   binstart      = bsumB + 1024;             // NBIN+1 (+pad)
    unsigned* row_desc   = (unsigned*)(binstart + NBIN + 8);  // NN

    const int BS = 256;
    const int grid_spmm = (NN * 16 + BS - 1) / BS;   // 3125

    // ---- (chunk,bin) histogram (+fused input transpose) + bin-major scan ----
    hist_kernel<<<NBLK1 + TIN_BLKS, BS, 0, stream>>>(row, hist1, x, xt16);
    scan_local_kernel<<<SCAN_NBLK, BS, 0, stream>>>(hist1, NH, bsumB);
    scanfin_kernel<<<SCAN_NBLK, BS, 0, stream>>>(hist1, NH, bsumB, SCAN_NBLK, binstart);

    // ---- two-pass sort: bin-group then padded per-row placement ----
    pass1_kernel<<<NBLK1, BS, 0, stream>>>(row, col, adj_vals, w_vals,
                                           hist1, k1, aw1);
    pass2_kernel<<<NBIN, BS, 0, stream>>>(k1, aw1, binstart, kvA2, kvW2, row_desc);

    const uint2* kvA = (const uint2*)kvA2;
    const uint2* kvW = (const uint2*)kvW2;
    const unsigned* xt32  = (const unsigned*)xt16;
    unsigned*       xt32w = (unsigned*)xt16;
    const unsigned* tm32  = (const unsigned*)tmp16;
    unsigned*       tm32w = (unsigned*)tmp16;

    // ---- dense passes (scaled fp16 state: state_l = xt_l * 256^-l) ----
    const float r256 = 1.0f / 256.0f;
    spmm_kernel<0, 0><<<grid_spmm, BS, 0, stream>>>(kvW, row_desc, xt32, tm32w,
                                                    nullptr, 1.0f, 0.0f, nullptr);
    spmm_kernel<1, 0><<<grid_spmm, BS, 0, stream>>>(kvA, row_desc, tm32, xt32w,
                                                    bias, r256, 1.0f / 256.0f, nullptr);
    spmm_kernel<0, 0><<<grid_spmm, BS, 0, stream>>>(kvW, row_desc, xt32, tm32w,
                                                    nullptr, 1.0f, 0.0f, nullptr);
    spmm_kernel<1, 0><<<grid_spmm, BS, 0, stream>>>(kvA, row_desc, tm32, xt32w,
                                                    bias, r256, 1.0f / 65536.0f, nullptr);
    spmm_kernel<0, 0><<<grid_spmm, BS, 0, stream>>>(kvW, row_desc, xt32, tm32w,
                                                    nullptr, 1.0f, 0.0f, nullptr);
    spmm_kernel<1, 1><<<grid_spmm, BS, 0, stream>>>(kvA, row_desc, tm32, xt32w,
                                                    bias, r256, 1.0f / 16777216.0f, out);
}